// Round 6
// baseline (51.765 us; speedup 1.0000x reference)
//
#include <hip/hip_runtime.h>
#include <math.h>

#define TRI_EPS 1e-4f

// ---------- prep: per-face gather + precompute (6 float4 per face) ----------
// [0]=a,inv1  [1]=b,inv2  [2]=c,inv3  [3]=e1  [4]=e2  [5]=e3
// Also: init keys/hits (separate launch from main => no race), block 0 vmean.
__global__ __launch_bounds__(256) void prep_kernel(
    const float* __restrict__ v, const int* __restrict__ f,
    float4* __restrict__ fdat, float* __restrict__ vm,
    unsigned long long* __restrict__ keys, int* __restrict__ hcnt,
    int V, int F, int N) {
    const int t = threadIdx.x;
    const int j = blockIdx.x * 256 + t;
    if (j < N) {
        keys[j] = 0xFFFFFFFFFFFFFFFFull;
        hcnt[j] = 0;
    }
    if (j < F) {
        const int i0 = f[3 * j + 0];
        const int i1 = f[3 * j + 1];
        const int i2 = f[3 * j + 2];
        const float ax = v[3 * i0 + 0], ay = v[3 * i0 + 1], az = v[3 * i0 + 2];
        const float bx = v[3 * i1 + 0], by = v[3 * i1 + 1], bz = v[3 * i1 + 2];
        const float cx = v[3 * i2 + 0], cy = v[3 * i2 + 1], cz = v[3 * i2 + 2];
        const float e1x = ax - bx, e1y = ay - by, e1z = az - bz;
        const float e2x = cx - bx, e2y = cy - by, e2z = cz - bz;
        const float e3x = cx - ax, e3y = cy - ay, e3z = cz - az;
        const float m1 = e1x * e1x + e1y * e1y + e1z * e1z;
        const float m2 = e2x * e2x + e2y * e2y + e2z * e2z;
        const float m3 = e3x * e3x + e3y * e3y + e3z * e3z;
        fdat[6 * j + 0] = make_float4(ax, ay, az, 1.f / m1);
        fdat[6 * j + 1] = make_float4(bx, by, bz, 1.f / m2);
        fdat[6 * j + 2] = make_float4(cx, cy, cz, 1.f / m3);
        fdat[6 * j + 3] = make_float4(e1x, e1y, e1z, 0.f);
        fdat[6 * j + 4] = make_float4(e2x, e2y, e2z, 0.f);
        fdat[6 * j + 5] = make_float4(e3x, e3y, e3z, 0.f);
    }
    if (blockIdx.x == 0) {
        __shared__ float sx[256], sy[256], sz[256];
        float x = 0.f, y = 0.f, z = 0.f;
        for (int i = t; i < V; i += 256) {
            x += v[3 * i + 0];
            y += v[3 * i + 1];
            z += v[3 * i + 2];
        }
        sx[t] = x; sy[t] = y; sz[t] = z;
        __syncthreads();
        for (int off = 128; off > 0; off >>= 1) {
            if (t < off) {
                sx[t] += sx[t + off];
                sy[t] += sy[t + off];
                sz[t] += sz[t + off];
            }
            __syncthreads();
        }
        if (t == 0) {
            vm[0] = sx[0] / (float)V;
            vm[1] = sy[0] / (float)V;
            vm[2] = sz[0] / (float)V;
        }
    }
}

// ---------- shared arithmetic (VERBATIM — bit-stable across rounds) --------
struct FP {
    float d1, d2, d3;
    float x1, y1, z1, x2, y2, z2, x3, y3, z3;
    float apx, apy, apz;
};

__device__ __forceinline__ FP face_point(
    const float4 ra, const float4 rb, const float4 rc,
    const float e1x, const float e1y, const float e1z,
    const float e2x, const float e2y, const float e2z,
    const float e3x, const float e3y, const float e3z,
    const float px, const float py, const float pz) {
    FP r;
    const float ax = ra.x, ay = ra.y, az = ra.z;
    const float bx = rb.x, by = rb.y, bz = rb.z;
    const float cx = rc.x, cy = rc.y, cz = rc.z;
    r.apx = ax - px; r.apy = ay - py; r.apz = az - pz;
    const float cpx = cx - px, cpy = cy - py, cpz = cz - pz;

    float s1 = (r.apx * e1x + r.apy * e1y + r.apz * e1z) * ra.w;
    s1 = fminf(fmaxf(s1, 0.f), 1.f);
    const float o1 = 1.f - s1;
    r.x1 = s1 * bx + o1 * ax;
    r.y1 = s1 * by + o1 * ay;
    r.z1 = s1 * bz + o1 * az;
    float ux = r.x1 - px, uy = r.y1 - py, uz = r.z1 - pz;
    r.d1 = ux * ux + uy * uy + uz * uz;

    float s2 = (cpx * e2x + cpy * e2y + cpz * e2z) * rb.w;
    s2 = fminf(fmaxf(s2, 0.f), 1.f);
    const float o2 = 1.f - s2;
    r.x2 = s2 * bx + o2 * cx;
    r.y2 = s2 * by + o2 * cy;
    r.z2 = s2 * bz + o2 * cz;
    ux = r.x2 - px; uy = r.y2 - py; uz = r.z2 - pz;
    r.d2 = ux * ux + uy * uy + uz * uz;

    float s3 = (cpx * e3x + cpy * e3y + cpz * e3z) * rc.w;
    s3 = fminf(fmaxf(s3, 0.f), 1.f);
    const float o3 = 1.f - s3;
    r.x3 = s3 * ax + o3 * cx;
    r.y3 = s3 * ay + o3 * cy;
    r.z3 = s3 * az + o3 * cz;
    ux = r.x3 - px; uy = r.y3 - py; uz = r.z3 - pz;
    r.d3 = ux * ux + uy * uy + uz * uz;
    return r;
}

__device__ __forceinline__ void pair_update(
    const float4 ra, const float4 rb, const float4 rc,
    const float e1x, const float e1y, const float e1z,
    const float e2x, const float e2y, const float e2z,
    const float e3x, const float e3y, const float e3z,
    const float px, const float py, const float pz,
    const float dx, const float dy, const float dz, const int j,
    float& bd2, int& bid, int& hits) {
    const FP r = face_point(ra, rb, rc, e1x, e1y, e1z, e2x, e2y, e2z,
                            e3x, e3y, e3z, px, py, pz);
    float fd2 = r.d1; int eid = 0;
    if (r.d2 < fd2) { fd2 = r.d2; eid = 1; }
    if (r.d3 < fd2) { fd2 = r.d3; eid = 2; }
    if (fd2 < bd2) { bd2 = fd2; bid = (j << 2) | eid; }

    const float pvx = dy * e3z - dz * e3y;
    const float pvy = dz * e3x - dx * e3z;
    const float pvz = dx * e3y - dy * e3x;
    const float det = -(e1x * pvx + e1y * pvy + e1z * pvz);
    const float tu = -(r.apx * pvx + r.apy * pvy + r.apz * pvz);
    const float qvx = r.apy * e1z - r.apz * e1y;
    const float qvy = r.apz * e1x - r.apx * e1z;
    const float qvz = r.apx * e1y - r.apy * e1x;
    const float td = dx * qvx + dy * qvy + dz * qvz;
    const float tn = e3x * qvx + e3y * qvy + e3z * qvz;
    const float adet = fabsf(det);
    const float sd = (det > 0.f) ? 1.f : -1.f;
    const float su = tu * sd;
    const float sq = td * sd;
    const float st = tn * sd;
    if (adet > TRI_EPS && su >= 0.f && su <= adet && sq >= 0.f &&
        (su + sq) <= adet && st > TRI_EPS * adet)
        hits++;
}

// ---------- main (specialized): LDS-staged chunk, 2 points per lane --------
template <int CS>
__global__ __launch_bounds__(256) void sdf_main_t(
    const float* __restrict__ p, const float4* __restrict__ fd,
    const float* __restrict__ vm,
    unsigned long long* __restrict__ keys, int* __restrict__ hcnt,
    int N, int C) {
    __shared__ float4 sfd[6 * CS];
    const int t = threadIdx.x;
    const int k = blockIdx.x % C;    // face chunk
    const int pg = blockIdx.x / C;   // point group (512 points)
    const int j0 = k * CS;

    if (t < 6 * CS) sfd[t] = fd[6 * j0 + t];   // 1.5 KB coalesced burst

    const int i0 = pg * 512 + t;
    const int i1 = i0 + 256;
    const bool vA = (i0 < N);
    const bool vB = (i1 < N);
    const int lA = vA ? i0 : 0;
    const int lB = vB ? i1 : 0;
    const float pAx = p[3 * lA + 0], pAy = p[3 * lA + 1], pAz = p[3 * lA + 2];
    const float pBx = p[3 * lB + 0], pBy = p[3 * lB + 1], pBz = p[3 * lB + 2];
    const float vmx = vm[0], vmy = vm[1], vmz = vm[2];
    const float dAx = vmx - pAx, dAy = vmy - pAy, dAz = vmz - pAz;
    const float dBx = vmx - pBx, dBy = vmy - pBy, dBz = vmz - pBz;

    float Ad2 = INFINITY; int Aid = 0x7fffffff; int Ah = 0;
    float Bd2 = INFINITY; int Bid = 0x7fffffff; int Bh = 0;

    __syncthreads();

    #pragma unroll 4
    for (int jj = 0; jj < CS; ++jj) {
        const float4 ra  = sfd[6 * jj + 0];
        const float4 rb  = sfd[6 * jj + 1];
        const float4 rc  = sfd[6 * jj + 2];
        const float4 re1 = sfd[6 * jj + 3];
        const float4 re2 = sfd[6 * jj + 4];
        const float4 re3 = sfd[6 * jj + 5];
        const int j = j0 + jj;
        pair_update(ra, rb, rc, re1.x, re1.y, re1.z, re2.x, re2.y, re2.z,
                    re3.x, re3.y, re3.z, pAx, pAy, pAz, dAx, dAy, dAz, j,
                    Ad2, Aid, Ah);
        pair_update(ra, rb, rc, re1.x, re1.y, re1.z, re2.x, re2.y, re2.z,
                    re3.x, re3.y, re3.z, pBx, pBy, pBz, dBx, dBy, dBz, j,
                    Bd2, Bid, Bh);
    }

    if (vA) {
        const unsigned long long keyA =
            ((unsigned long long)__float_as_uint(Ad2) << 32) | (unsigned int)Aid;
        atomicMin(&keys[i0], keyA);
        if (Ah) atomicAdd(&hcnt[i0], Ah);
    }
    if (vB) {
        const unsigned long long keyB =
            ((unsigned long long)__float_as_uint(Bd2) << 32) | (unsigned int)Bid;
        atomicMin(&keys[i1], keyB);
        if (Bh) atomicAdd(&hcnt[i1], Bh);
    }
}

// ---------- main (generic fallback, runtime chunk size) --------------------
__global__ __launch_bounds__(256) void sdf_main_g(
    const float* __restrict__ p, const float4* __restrict__ fd,
    const float* __restrict__ vm,
    unsigned long long* __restrict__ keys, int* __restrict__ hcnt,
    int N, int F, int C, int CS) {
    const int k = blockIdx.x % C;
    const int pg = blockIdx.x / C;
    const int i = pg * 256 + threadIdx.x;
    if (i >= N) return;
    const float px = p[3 * i + 0];
    const float py = p[3 * i + 1];
    const float pz = p[3 * i + 2];
    const float dx = vm[0] - px;
    const float dy = vm[1] - py;
    const float dz = vm[2] - pz;
    float bd2 = INFINITY; int bid = 0x7fffffff; int hits = 0;
    const int j0 = k * CS;
    const int j1 = min(F, j0 + CS);
    for (int j = j0; j < j1; ++j) {
        const float4 ra  = fd[6 * j + 0];
        const float4 rb  = fd[6 * j + 1];
        const float4 rc  = fd[6 * j + 2];
        const float4 re1 = fd[6 * j + 3];
        const float4 re2 = fd[6 * j + 4];
        const float4 re3 = fd[6 * j + 5];
        pair_update(ra, rb, rc, re1.x, re1.y, re1.z, re2.x, re2.y, re2.z,
                    re3.x, re3.y, re3.z, px, py, pz, dx, dy, dz, j,
                    bd2, bid, hits);
    }
    const unsigned long long key =
        ((unsigned long long)__float_as_uint(bd2) << 32) | (unsigned int)bid;
    atomicMin(&keys[i], key);
    if (hits) atomicAdd(&hcnt[i], hits);
}

// ---------- epilogue: unpack winner, recompute closest point, sign ---------
__global__ __launch_bounds__(256) void sdf_epilogue(
    const float* __restrict__ p, const float4* __restrict__ fd,
    const unsigned long long* __restrict__ keys, const int* __restrict__ hcnt,
    float* __restrict__ out, int N) {
    const int i = blockIdx.x * 256 + threadIdx.x;
    if (i >= N) return;
    const unsigned long long key = keys[i];
    const float bd2 = __uint_as_float((unsigned int)(key >> 32));
    const int bid = (int)(unsigned int)(key & 0xFFFFFFFFull);
    const int jw = bid >> 2;
    const int eid = bid & 3;
    const float px = p[3 * i + 0];
    const float py = p[3 * i + 1];
    const float pz = p[3 * i + 2];
    const float4 wa  = fd[6 * jw + 0];
    const float4 wb  = fd[6 * jw + 1];
    const float4 wc  = fd[6 * jw + 2];
    const float4 we1 = fd[6 * jw + 3];
    const float4 we2 = fd[6 * jw + 4];
    const float4 we3 = fd[6 * jw + 5];
    const FP r = face_point(wa, wb, wc, we1.x, we1.y, we1.z,
                            we2.x, we2.y, we2.z, we3.x, we3.y, we3.z,
                            px, py, pz);
    float clx = r.x1, cly = r.y1, clz = r.z1;
    if (eid == 1) { clx = r.x2; cly = r.y2; clz = r.z2; }
    if (eid == 2) { clx = r.x3; cly = r.y3; clz = r.z3; }
    const float d = sqrtf(bd2);
    out[i] = (hcnt[i] & 1) ? -d : d;
    out[N + 3 * i + 0] = clx;
    out[N + 3 * i + 1] = cly;
    out[N + 3 * i + 2] = clz;
}

extern "C" void kernel_launch(void* const* d_in, const int* in_sizes, int n_in,
                              void* d_out, int out_size, void* d_ws,
                              size_t ws_size, hipStream_t stream) {
    const float* p = (const float*)d_in[0];
    const float* v = (const float*)d_in[1];
    const int* f = (const int*)d_in[2];
    float* out = (float*)d_out;

    const int N = in_sizes[0] / 3;
    const int V = in_sizes[1] / 3;
    const int F = in_sizes[2] / 3;

    // workspace: vm[4] | keys[N] u64 | hcnt[N] i32 | fdat[6F] float4
    char* base = (char*)d_ws;
    float* vm = (float*)base;
    unsigned long long* keys = (unsigned long long*)(base + 16);
    int* hcnt = (int*)(base + 16 + 8ull * N);
    size_t off = 16 + 12ull * N;
    off = (off + 15) & ~15ull;
    float4* fdat = (float4*)(base + off);

    const int C = 256;
    const int gprep = (max(F, N) + 255) / 256;
    prep_kernel<<<gprep, 256, 0, stream>>>(v, f, fdat, vm, keys, hcnt, V, F, N);

    if (F == C * 16) {
        const int npg = (N + 511) / 512;
        sdf_main_t<16><<<npg * C, 256, 0, stream>>>(p, fdat, vm, keys, hcnt,
                                                    N, C);
    } else {
        const int CS = (F + C - 1) / C;
        const int npg = (N + 255) / 256;
        sdf_main_g<<<npg * C, 256, 0, stream>>>(p, fdat, vm, keys, hcnt,
                                                N, F, C, CS);
    }
    sdf_epilogue<<<(N + 255) / 256, 256, 0, stream>>>(p, fdat, keys, hcnt,
                                                      out, N);
}